// Round 8
// baseline (693.125 us; speedup 1.0000x reference)
//
#include <hip/hip_runtime.h>

// FEM stiffness matvec KU = sum_e scatter(K_type(e) @ gather(U, e)).
//
// Round 22 = R16 base (212.0 us; K1 71.5 us) MINUS the barrier structure:
// per-record global atomicAdd binning with 4 sub-counters per bucket.
// R21 post-mortem (K1 82 us): fp16 b64 filter reads conflict WORSE per byte
// (7.55M->12.4M cycles); fp32 b128 is the right LDS granule. Six variants
// (sort/global-K/half-table/2x512/fp16) all lost to R16; all attacked
// LDS/VALU/occupancy which the triad (VALU 19%, HBM 36%, Occ 36%) says are
// non-critical. UNTESTED until now: the 3-barrier block-sync structure.
// With 16 waves in ONE block, each __syncthreads drains vmcnt(0) over 16
// random-latency gathers (L2 ~200 / HBM ~900 cyc) and waits for the
// straggler wave - twice per kernel (m114/m131: the structural ~20%).
// R22: delete pass A counting + pass B reservation + both data barriers.
// Dense positions come from atomicAdd(&tails[bucket*4 + blockIdx&3], 1);
// 4 sub-counters -> ~2K increments each on independent L2 lines; records
// region = 4 runs of CAP_SUB=2560 (mean 2045 + 13 sigma; overflow -> exact
// fp32 KU atomics). K2 walks the 4 segments. Also removes 16M LDS counting
// atomics (part of the 7.55M conflict cycles). One barrier remains (filter
// staging). Threads flow freely: compute starts when OWN gathers return.
// Carries: fp32 LDS filters stride 580 b128, EPT 2 early gather issue,
// bf16-packed U, 8 B records, K2_TPB 1024, launch_bounds(1024,4)
// (VGPR law: cap = 256/(waves/EU); never cap below body ~52 - R10/R19).
// R15: element order is the locality asset. nodIdx is uniform random ->
// gathers irreducible. ~110 us of total is harness fixed (R13).

#define NTYPES    64
#define KSTRIDE   580            // fp32 words per type: 2320 B, 16 B-aligned
#define RSHIFT    11
#define RNODES    2048
#define MAXB      512
#define NSUB      4              // sub-counters per bucket (blockIdx & 3)
#define CAP       10240          // records per bucket total
#define CAP_SUB   2560           // per sub-counter run (mean 2045 + 13 sigma)
#define K1_TPB    1024
#define K1_EPT    2
#define K1_CHUNK  (K1_TPB * K1_EPT)
#define K2_TPB    1024
#define PREP_TPB  256

typedef int          nint4  __attribute__((ext_vector_type(4)));
typedef unsigned int nuint2 __attribute__((ext_vector_type(2)));
typedef unsigned int nuint4 __attribute__((ext_vector_type(4)));

__device__ __forceinline__ unsigned bf16_rne(float f) {
    unsigned b = __float_as_uint(f);
    return (b + 0x7FFFu + ((b >> 16) & 1u)) >> 16;
}

// ---- phase 0: pack U -> bf16 triples; zero KU and tails -------------------

__global__ __launch_bounds__(PREP_TPB) void pack_u_kernel(
    const float* __restrict__ U, nuint2* __restrict__ Ub,
    float* __restrict__ KU, unsigned* __restrict__ tails,
    int n_nodes, int n_buckets)
{
    int n = blockIdx.x * PREP_TPB + threadIdx.x;
    if (n < n_buckets * NSUB) tails[n] = 0;
    if (n >= n_nodes) return;
    const float* up = U + (size_t)n * 3;
    unsigned bx = bf16_rne(up[0]);
    unsigned by = bf16_rne(up[1]);
    unsigned bz = bf16_rne(up[2]);
    nuint2 v = { bx | (by << 16), bz };
    Ub[n] = v;
    KU[3 * n + 0] = 0.f;
    KU[3 * n + 1] = 0.f;
    KU[3 * n + 2] = 0.f;
}

// ---- phase 1: compute + bin (barrier-free, global sub-counter atomics) ---

__global__ __launch_bounds__(K1_TPB, 4) void feconv_bin_kernel(
    const nuint2* __restrict__ Ub,      // [N] packed bf16 x,y,z
    const float* __restrict__ K,        // [64, 24, 24]
    const int*   __restrict__ types,    // [E]
    const int*   __restrict__ nodIdx,   // [E, 8]
    float*       __restrict__ KU,       // overflow fallback only
    unsigned*    __restrict__ tails,    // [n_buckets * NSUB]
    nuint2*      __restrict__ recs,     // [n_buckets * CAP]
    int n_elems, int n_buckets)
{
    extern __shared__ float sK[];       // [64 * KSTRIDE] words, per-type rows

    for (int w = threadIdx.x; w < NTYPES * 576; w += K1_TPB) {
        int t = w / 576;
        int r = w - t * 576;
        sK[t * KSTRIDE + r] = K[w];
    }
    __syncthreads();                    // the ONLY barrier

    const unsigned sub = (unsigned)(blockIdx.x & (NSUB - 1));
    const int e0 = blockIdx.x * K1_CHUNK + threadIdx.x;
    int     nodes[K1_EPT][8];
    int     tt[K1_EPT];
    nuint2  uu[K1_EPT][8];              // in-flight packed gathers

    // issue all connectivity + gathers up front (16 loads in flight);
    // no barrier follows - each thread's compute starts when ITS gathers land
#pragma unroll
    for (int k = 0; k < K1_EPT; ++k) {
        int e = e0 + k * K1_TPB;
        tt[k] = -1;
        if (e < n_elems) {
            tt[k] = __builtin_nontemporal_load(&types[e]);
            const nint4* q = (const nint4*)(nodIdx + (size_t)e * 8);
            nint4 a = __builtin_nontemporal_load(q);
            nint4 b = __builtin_nontemporal_load(q + 1);
            nodes[k][0] = a.x; nodes[k][1] = a.y; nodes[k][2] = a.z; nodes[k][3] = a.w;
            nodes[k][4] = b.x; nodes[k][5] = b.y; nodes[k][6] = b.z; nodes[k][7] = b.w;
#pragma unroll
            for (int j = 0; j < 8; ++j)
                uu[k][j] = Ub[nodes[k][j]];          // issue all 16 gathers now
        }
    }

    // compute + write records; position via global sub-counter atomicAdd
#pragma unroll
    for (int k = 0; k < K1_EPT; ++k) {
        if (tt[k] < 0) continue;

        float ue[24];
#pragma unroll
        for (int j = 0; j < 8; ++j) {
            nuint2 v = uu[k][j];
            ue[3 * j + 0] = __uint_as_float(v.x << 16);
            ue[3 * j + 1] = __uint_as_float(v.x & 0xFFFF0000u);
            ue[3 * j + 2] = __uint_as_float(v.y << 16);
        }

        const float4* Kt4 = (const float4*)(sK + tt[k] * KSTRIDE);
#pragma unroll
        for (int j = 0; j < 8; ++j) {
            float a0 = 0.f, a1 = 0.f, a2 = 0.f;
#pragma unroll
            for (int q = 0; q < 6; ++q) {
                float4 k0 = Kt4[(3 * j + 0) * 6 + q];
                float4 k1 = Kt4[(3 * j + 1) * 6 + q];
                float4 k2 = Kt4[(3 * j + 2) * 6 + q];
                float u0 = ue[4 * q + 0], u1 = ue[4 * q + 1];
                float u2 = ue[4 * q + 2], u3 = ue[4 * q + 3];
                a0 += k0.x * u0 + k0.y * u1 + k0.z * u2 + k0.w * u3;
                a1 += k1.x * u0 + k1.y * u1 + k1.z * u2 + k1.w * u3;
                a2 += k2.x * u0 + k2.y * u1 + k2.z * u2 + k2.w * u3;
            }
            unsigned n = (unsigned)nodes[k][j];
            unsigned b = n >> RSHIFT;
            unsigned pos = atomicAdd(&tails[b * NSUB + sub], 1u);
            if (pos < CAP_SUB) {
                unsigned local = n & (RNODES - 1);
                nuint2 r = { bf16_rne(a0) | (bf16_rne(a1) << 16),
                             bf16_rne(a2) | (local << 16) };
                recs[(size_t)b * CAP + sub * CAP_SUB + pos] = r;
            } else {  // statistically unreachable; absolute correctness
                atomicAdd(&KU[(size_t)n * 3 + 0], a0);
                atomicAdd(&KU[(size_t)n * 3 + 1], a1);
                atomicAdd(&KU[(size_t)n * 3 + 2], a2);
            }
        }
    }
}

// ---- phase 2: accumulate per bucket (4 segments) -------------------------

__global__ __launch_bounds__(K2_TPB) void feconv_acc_kernel(
    const nuint2*   __restrict__ recs,
    const unsigned* __restrict__ tails,  // [n_buckets * NSUB]
    float*          __restrict__ KU,     // [N, 3], pre-zeroed
    int n_nodes)
{
    __shared__ float sAcc[RNODES * 3];   // 24 KB; TPB 1024 -> 2 blocks/CU
    const int b = blockIdx.x;

    for (int i = threadIdx.x; i < RNODES * 3; i += K2_TPB) sAcc[i] = 0.f;
    __syncthreads();

#pragma unroll
    for (int s = 0; s < NSUB; ++s) {
        unsigned cnt = tails[b * NSUB + s];
        if (cnt > CAP_SUB) cnt = CAP_SUB;
        const nuint2* base = recs + (size_t)b * CAP + (size_t)s * CAP_SUB;
        const nuint4* base4 = (const nuint4*)base;   // 16 B-aligned (CAP_SUB even)

        unsigned npairs = cnt >> 1;
        for (unsigned i = threadIdx.x; i < npairs; i += K2_TPB) {
            nuint4 p = base4[i];                      // two records, one load
            unsigned o0 = (p.y >> 16) * 3;
            atomicAdd(&sAcc[o0 + 0], __uint_as_float(p.x << 16));
            atomicAdd(&sAcc[o0 + 1], __uint_as_float(p.x & 0xFFFF0000u));
            atomicAdd(&sAcc[o0 + 2], __uint_as_float(p.y << 16));
            unsigned o1 = (p.w >> 16) * 3;
            atomicAdd(&sAcc[o1 + 0], __uint_as_float(p.z << 16));
            atomicAdd(&sAcc[o1 + 1], __uint_as_float(p.z & 0xFFFF0000u));
            atomicAdd(&sAcc[o1 + 2], __uint_as_float(p.w << 16));
        }
        if ((cnt & 1u) && threadIdx.x == 0) {         // odd tail record
            nuint2 r = base[cnt - 1];
            unsigned o = (r.y >> 16) * 3;
            atomicAdd(&sAcc[o + 0], __uint_as_float(r.x << 16));
            atomicAdd(&sAcc[o + 1], __uint_as_float(r.x & 0xFFFF0000u));
            atomicAdd(&sAcc[o + 2], __uint_as_float(r.y << 16));
        }
    }
    __syncthreads();

    const int nbase = b * RNODES;
    int limit = n_nodes - nbase;
    if (limit > RNODES) limit = RNODES;
    limit *= 3;
    float* out = KU + (size_t)nbase * 3;
    for (int i = threadIdx.x; i < limit; i += K2_TPB) out[i] += sAcc[i];
}

// ---- fallback (round-0 style) --------------------------------------------

__global__ __launch_bounds__(256) void feconv_elem_kernel(
    const float* __restrict__ U, const float* __restrict__ K,
    const int* __restrict__ types, const int* __restrict__ nodIdx,
    float* __restrict__ KU, int n_elems)
{
    int e = blockIdx.x * blockDim.x + threadIdx.x;
    if (e >= n_elems) return;
    int t = types[e];
    const int4* idx4 = (const int4*)(nodIdx + (size_t)e * 8);
    int4 iA = idx4[0], iB = idx4[1];
    int nodes[8] = {iA.x, iA.y, iA.z, iA.w, iB.x, iB.y, iB.z, iB.w};
    float ue[24];
#pragma unroll
    for (int j = 0; j < 8; ++j) {
        const float* up = U + (size_t)nodes[j] * 3;
        ue[3 * j + 0] = up[0]; ue[3 * j + 1] = up[1]; ue[3 * j + 2] = up[2];
    }
    const float* Kt = K + (size_t)t * 576;
#pragma unroll
    for (int i = 0; i < 24; ++i) {
        const float4* row = (const float4*)(Kt + i * 24);
        float acc = 0.f;
#pragma unroll
        for (int q = 0; q < 6; ++q) {
            float4 k = row[q];
            acc += k.x * ue[4 * q + 0] + k.y * ue[4 * q + 1]
                 + k.z * ue[4 * q + 2] + k.w * ue[4 * q + 3];
        }
        atomicAdd(&KU[(size_t)nodes[i / 3] * 3 + (i % 3)], acc);
    }
}

extern "C" void kernel_launch(void* const* d_in, const int* in_sizes, int n_in,
                              void* d_out, int out_size, void* d_ws, size_t ws_size,
                              hipStream_t stream) {
    const float* U      = (const float*)d_in[0];
    const float* Kf     = (const float*)d_in[1];
    const int*   types  = (const int*)d_in[2];
    const int*   nodIdx = (const int*)d_in[3];
    float*       KU     = (float*)d_out;

    const int n_elems = in_sizes[2];
    const int n_nodes = in_sizes[0] / 3;
    const int n_buckets = (n_nodes + RNODES - 1) / RNODES;   // 489 for N=1M

    // ws layout: [0, 8192) tails[489*4] | [8192, +8B*n_nodes) Ub | then recs
    const size_t ub_off  = 8192;
    const size_t rec_off = ub_off + (((size_t)n_nodes * 8 + 255) & ~255ull);
    const size_t need    = rec_off + (size_t)n_buckets * CAP * 8;

    if (n_buckets <= MAXB && ws_size >= need) {
        unsigned* tails = (unsigned*)d_ws;
        nuint2*   Ub    = (nuint2*)((char*)d_ws + ub_off);
        nuint2*   recs  = (nuint2*)((char*)d_ws + rec_off);

        int gridP = (n_nodes + PREP_TPB - 1) / PREP_TPB;
        pack_u_kernel<<<gridP, PREP_TPB, 0, stream>>>(
            U, Ub, KU, tails, n_nodes, n_buckets);

        size_t lds_bytes = (size_t)NTYPES * KSTRIDE * sizeof(float);  // 148,480
        int grid1 = (n_elems + K1_CHUNK - 1) / K1_CHUNK;               // 245
        feconv_bin_kernel<<<grid1, K1_TPB, lds_bytes, stream>>>(
            Ub, Kf, types, nodIdx, KU, tails, recs, n_elems, n_buckets);
        feconv_acc_kernel<<<n_buckets, K2_TPB, 0, stream>>>(
            recs, tails, KU, n_nodes);
    } else {
        (void)hipMemsetAsync(KU, 0, (size_t)out_size * sizeof(float), stream);
        int block = 256;
        int grid = (n_elems + block - 1) / block;
        feconv_elem_kernel<<<grid, block, 0, stream>>>(
            U, Kf, types, nodIdx, KU, n_elems);
    }
}

// Round 9
// 224.768 us; speedup vs baseline: 3.0837x; 3.0837x over previous
//
#include <hip/hip_runtime.h>

// FEM stiffness matvec KU = sum_e scatter(K_type(e) @ gather(U, e)).
//
// Round 23 = EXACT R16 champion (211.96 us; K1 71.5 us) + ONE scheduling
// delta: Ub gather issue moved from pass A to the start of pass C.
// R22 post-mortem (K1 551 us): value-returning global atomicAdd on the
// per-record path = ~600cyc serialized round-trip x16/thread. RULE: never
// put a returning atomic on the per-item path; reserve at block level.
// R23 mechanism (the theory R22 meant to test, surgically): in R16, pass A
// issues 16 random-latency Ub gathers and then __syncthreads forces
// s_waitcnt vmcnt(0) -> every wave drains 16 loads (L2 ~200 / L3 ~500-900
// cyc) and the block waits for the slowest wave - at TWO barriers. The
// gathers are thread-private; they need not complete at any barrier.
// Moving the issue after the last barrier: pass A's types/nodIdx loads are
// consumed in-pass (vmcnt naturally ~0 at barrier -> sync-only cost), and
// gather latency in pass C hides under cross-wave compute overlap (16
// waves x ~1150 ops/element). Identical traffic, identical instruction
// mix; only issue order changes.
// Failed-variant ledger (all vs R16): R15 global sort (DRAM 2.8x), R17
// local sort (FETCH +20MB, conflicts not critical), R18 global-K via L1
// (VMEM thrash), R19 (1024,8) VGPR 32 spill, R20 fp16 2x512 (didn't
// co-reside, 81.4KB x2 > usable LDS), R21 fp16 b64 (conflicts 12.4M,
// wrong granule), R22 returning atomics (serialized).
// Carries: fp32 LDS filters stride 580 b128, EPT 2, bf16-packed U, 8 B
// records, block tail reservation, K2_TPB 1024, launch_bounds(1024,4)
// (VGPR law: cap = 256/(waves/EU); body ~56 -> 4 waves/EU max).
// nodIdx is uniform random -> gathers irreducible; element order is the
// locality asset (R15). ~110 us of total is harness fixed (R13).

#define NTYPES    64
#define KSTRIDE   580            // fp32 words per type: 2320 B, 16 B-aligned
#define RSHIFT    11
#define RNODES    2048
#define MAXB      512
#define CAP       10240          // mean 8180/bucket, huge slack (even: 16 B pairs)
#define K1_TPB    1024
#define K1_EPT    2
#define K1_CHUNK  (K1_TPB * K1_EPT)
#define K2_TPB    1024
#define PREP_TPB  256

typedef int          nint4  __attribute__((ext_vector_type(4)));
typedef unsigned int nuint2 __attribute__((ext_vector_type(2)));
typedef unsigned int nuint4 __attribute__((ext_vector_type(4)));

__device__ __forceinline__ unsigned bf16_rne(float f) {
    unsigned b = __float_as_uint(f);
    return (b + 0x7FFFu + ((b >> 16) & 1u)) >> 16;
}

// ---- phase 0: pack U -> bf16 triples; zero KU and tails -------------------

__global__ __launch_bounds__(PREP_TPB) void pack_u_kernel(
    const float* __restrict__ U, nuint2* __restrict__ Ub,
    float* __restrict__ KU, unsigned* __restrict__ tails,
    int n_nodes, int n_buckets)
{
    int n = blockIdx.x * PREP_TPB + threadIdx.x;
    if (n < n_buckets) tails[n] = 0;
    if (n >= n_nodes) return;
    const float* up = U + (size_t)n * 3;
    unsigned bx = bf16_rne(up[0]);
    unsigned by = bf16_rne(up[1]);
    unsigned bz = bf16_rne(up[2]);
    nuint2 v = { bx | (by << 16), bz };
    Ub[n] = v;
    KU[3 * n + 0] = 0.f;
    KU[3 * n + 1] = 0.f;
    KU[3 * n + 2] = 0.f;
}

// ---- phase 1: compute + bin ----------------------------------------------

__global__ __launch_bounds__(K1_TPB, 4) void feconv_bin_kernel(
    const nuint2* __restrict__ Ub,      // [N] packed bf16 x,y,z
    const float* __restrict__ K,        // [64, 24, 24]
    const int*   __restrict__ types,    // [E]
    const int*   __restrict__ nodIdx,   // [E, 8]
    float*       __restrict__ KU,       // overflow fallback only
    unsigned*    __restrict__ tails,    // [n_buckets]
    nuint2*      __restrict__ recs,     // [n_buckets * CAP]
    int n_elems, int n_buckets)
{
    extern __shared__ float sK[];       // [64 * KSTRIDE] words, per-type rows
    __shared__ unsigned sCnt[MAXB];
    __shared__ unsigned sBase[MAXB];

    for (int w = threadIdx.x; w < NTYPES * 576; w += K1_TPB) {
        int t = w / 576;
        int r = w - t * 576;
        sK[t * KSTRIDE + r] = K[w];
    }
    for (int i = threadIdx.x; i < n_buckets; i += K1_TPB) sCnt[i] = 0;
    __syncthreads();

    const int e0 = blockIdx.x * K1_CHUNK + threadIdx.x;
    int     nodes[K1_EPT][8];
    int     tt[K1_EPT];

    // pass A: connectivity + bucket counting ONLY. The types/nodIdx loads
    // are consumed here, so vmcnt is naturally ~0 at the barrier -> no
    // random-gather drain, barrier cost collapses to sync-only.
#pragma unroll
    for (int k = 0; k < K1_EPT; ++k) {
        int e = e0 + k * K1_TPB;
        tt[k] = -1;
        if (e < n_elems) {
            tt[k] = __builtin_nontemporal_load(&types[e]);
            const nint4* q = (const nint4*)(nodIdx + (size_t)e * 8);
            nint4 a = __builtin_nontemporal_load(q);
            nint4 b = __builtin_nontemporal_load(q + 1);
            nodes[k][0] = a.x; nodes[k][1] = a.y; nodes[k][2] = a.z; nodes[k][3] = a.w;
            nodes[k][4] = b.x; nodes[k][5] = b.y; nodes[k][6] = b.z; nodes[k][7] = b.w;
#pragma unroll
            for (int j = 0; j < 8; ++j)
                atomicAdd(&sCnt[(unsigned)nodes[k][j] >> RSHIFT], 1u);
        }
    }
    __syncthreads();

    // pass B: one global tail reservation per (block, bucket)
    for (int b = threadIdx.x; b < n_buckets; b += K1_TPB) {
        unsigned c = sCnt[b];
        sBase[b] = c ? atomicAdd(&tails[b], c) : 0u;
        sCnt[b] = 0;                     // reuse as local cursor
    }
    __syncthreads();

    // pass C: NOW issue all 16 gathers (after the last barrier - they are
    // never drained by a barrier; latency hides under cross-wave compute),
    // then unpack, matvec via ds_read_b128 filters, write 8 B records.
    nuint2 uu[K1_EPT][8];
#pragma unroll
    for (int k = 0; k < K1_EPT; ++k) {
        if (tt[k] >= 0) {
#pragma unroll
            for (int j = 0; j < 8; ++j)
                uu[k][j] = Ub[nodes[k][j]];
        }
    }

#pragma unroll
    for (int k = 0; k < K1_EPT; ++k) {
        if (tt[k] < 0) continue;

        float ue[24];
#pragma unroll
        for (int j = 0; j < 8; ++j) {
            nuint2 v = uu[k][j];
            ue[3 * j + 0] = __uint_as_float(v.x << 16);
            ue[3 * j + 1] = __uint_as_float(v.x & 0xFFFF0000u);
            ue[3 * j + 2] = __uint_as_float(v.y << 16);
        }

        const float4* Kt4 = (const float4*)(sK + tt[k] * KSTRIDE);
#pragma unroll
        for (int j = 0; j < 8; ++j) {
            float a0 = 0.f, a1 = 0.f, a2 = 0.f;
#pragma unroll
            for (int q = 0; q < 6; ++q) {
                float4 k0 = Kt4[(3 * j + 0) * 6 + q];
                float4 k1 = Kt4[(3 * j + 1) * 6 + q];
                float4 k2 = Kt4[(3 * j + 2) * 6 + q];
                float u0 = ue[4 * q + 0], u1 = ue[4 * q + 1];
                float u2 = ue[4 * q + 2], u3 = ue[4 * q + 3];
                a0 += k0.x * u0 + k0.y * u1 + k0.z * u2 + k0.w * u3;
                a1 += k1.x * u0 + k1.y * u1 + k1.z * u2 + k1.w * u3;
                a2 += k2.x * u0 + k2.y * u1 + k2.z * u2 + k2.w * u3;
            }
            unsigned n = (unsigned)nodes[k][j];
            unsigned b = n >> RSHIFT;
            unsigned pos = sBase[b] + atomicAdd(&sCnt[b], 1u);
            if (pos < CAP) {
                unsigned local = n & (RNODES - 1);
                nuint2 r = { bf16_rne(a0) | (bf16_rne(a1) << 16),
                             bf16_rne(a2) | (local << 16) };
                recs[(size_t)b * CAP + pos] = r;
            } else {  // statistically unreachable; absolute correctness
                atomicAdd(&KU[(size_t)n * 3 + 0], a0);
                atomicAdd(&KU[(size_t)n * 3 + 1], a1);
                atomicAdd(&KU[(size_t)n * 3 + 2], a2);
            }
        }
    }
}

// ---- phase 2: accumulate per bucket --------------------------------------

__global__ __launch_bounds__(K2_TPB) void feconv_acc_kernel(
    const nuint2*   __restrict__ recs,
    const unsigned* __restrict__ tails,
    float*          __restrict__ KU,     // [N, 3], pre-zeroed
    int n_nodes)
{
    __shared__ float sAcc[RNODES * 3];   // 24 KB; TPB 1024 -> 2 blocks/CU
    const int b = blockIdx.x;

    for (int i = threadIdx.x; i < RNODES * 3; i += K2_TPB) sAcc[i] = 0.f;
    __syncthreads();

    unsigned cnt = tails[b];
    if (cnt > CAP) cnt = CAP;
    const nuint2* base = recs + (size_t)b * CAP;
    const nuint4* base4 = (const nuint4*)base;       // 16 B-aligned (CAP even)

    unsigned npairs = cnt >> 1;
    for (unsigned i = threadIdx.x; i < npairs; i += K2_TPB) {
        nuint4 p = base4[i];                          // two records, one load
        unsigned o0 = (p.y >> 16) * 3;
        atomicAdd(&sAcc[o0 + 0], __uint_as_float(p.x << 16));
        atomicAdd(&sAcc[o0 + 1], __uint_as_float(p.x & 0xFFFF0000u));
        atomicAdd(&sAcc[o0 + 2], __uint_as_float(p.y << 16));
        unsigned o1 = (p.w >> 16) * 3;
        atomicAdd(&sAcc[o1 + 0], __uint_as_float(p.z << 16));
        atomicAdd(&sAcc[o1 + 1], __uint_as_float(p.z & 0xFFFF0000u));
        atomicAdd(&sAcc[o1 + 2], __uint_as_float(p.w << 16));
    }
    if ((cnt & 1u) && threadIdx.x == 0) {             // odd tail record
        nuint2 r = base[cnt - 1];
        unsigned o = (r.y >> 16) * 3;
        atomicAdd(&sAcc[o + 0], __uint_as_float(r.x << 16));
        atomicAdd(&sAcc[o + 1], __uint_as_float(r.x & 0xFFFF0000u));
        atomicAdd(&sAcc[o + 2], __uint_as_float(r.y << 16));
    }
    __syncthreads();

    const int nbase = b * RNODES;
    int limit = n_nodes - nbase;
    if (limit > RNODES) limit = RNODES;
    limit *= 3;
    float* out = KU + (size_t)nbase * 3;
    for (int i = threadIdx.x; i < limit; i += K2_TPB) out[i] += sAcc[i];
}

// ---- fallback (round-0 style) --------------------------------------------

__global__ __launch_bounds__(256) void feconv_elem_kernel(
    const float* __restrict__ U, const float* __restrict__ K,
    const int* __restrict__ types, const int* __restrict__ nodIdx,
    float* __restrict__ KU, int n_elems)
{
    int e = blockIdx.x * blockDim.x + threadIdx.x;
    if (e >= n_elems) return;
    int t = types[e];
    const int4* idx4 = (const int4*)(nodIdx + (size_t)e * 8);
    int4 iA = idx4[0], iB = idx4[1];
    int nodes[8] = {iA.x, iA.y, iA.z, iA.w, iB.x, iB.y, iB.z, iB.w};
    float ue[24];
#pragma unroll
    for (int j = 0; j < 8; ++j) {
        const float* up = U + (size_t)nodes[j] * 3;
        ue[3 * j + 0] = up[0]; ue[3 * j + 1] = up[1]; ue[3 * j + 2] = up[2];
    }
    const float* Kt = K + (size_t)t * 576;
#pragma unroll
    for (int i = 0; i < 24; ++i) {
        const float4* row = (const float4*)(Kt + i * 24);
        float acc = 0.f;
#pragma unroll
        for (int q = 0; q < 6; ++q) {
            float4 k = row[q];
            acc += k.x * ue[4 * q + 0] + k.y * ue[4 * q + 1]
                 + k.z * ue[4 * q + 2] + k.w * ue[4 * q + 3];
        }
        atomicAdd(&KU[(size_t)nodes[i / 3] * 3 + (i % 3)], acc);
    }
}

extern "C" void kernel_launch(void* const* d_in, const int* in_sizes, int n_in,
                              void* d_out, int out_size, void* d_ws, size_t ws_size,
                              hipStream_t stream) {
    const float* U      = (const float*)d_in[0];
    const float* Kf     = (const float*)d_in[1];
    const int*   types  = (const int*)d_in[2];
    const int*   nodIdx = (const int*)d_in[3];
    float*       KU     = (float*)d_out;

    const int n_elems = in_sizes[2];
    const int n_nodes = in_sizes[0] / 3;
    const int n_buckets = (n_nodes + RNODES - 1) / RNODES;   // 489 for N=1M

    // ws layout: [0, 4096) tails | [4096, +8B*n_nodes) Ub | then recs
    const size_t ub_off  = 4096;
    const size_t rec_off = ub_off + (((size_t)n_nodes * 8 + 255) & ~255ull);
    const size_t need    = rec_off + (size_t)n_buckets * CAP * 8;

    if (n_buckets <= MAXB && ws_size >= need) {
        unsigned* tails = (unsigned*)d_ws;
        nuint2*   Ub    = (nuint2*)((char*)d_ws + ub_off);
        nuint2*   recs  = (nuint2*)((char*)d_ws + rec_off);

        int gridP = (n_nodes + PREP_TPB - 1) / PREP_TPB;
        pack_u_kernel<<<gridP, PREP_TPB, 0, stream>>>(
            U, Ub, KU, tails, n_nodes, n_buckets);

        size_t lds_bytes = (size_t)NTYPES * KSTRIDE * sizeof(float);  // 148,480
        int grid1 = (n_elems + K1_CHUNK - 1) / K1_CHUNK;               // 245
        feconv_bin_kernel<<<grid1, K1_TPB, lds_bytes, stream>>>(
            Ub, Kf, types, nodIdx, KU, tails, recs, n_elems, n_buckets);
        feconv_acc_kernel<<<n_buckets, K2_TPB, 0, stream>>>(
            recs, tails, KU, n_nodes);
    } else {
        (void)hipMemsetAsync(KU, 0, (size_t)out_size * sizeof(float), stream);
        int block = 256;
        int grid = (n_elems + block - 1) / block;
        feconv_elem_kernel<<<grid, block, 0, stream>>>(
            U, Kf, types, nodIdx, KU, n_elems);
    }
}